// Round 18
// baseline (183.036 us; speedup 1.0000x reference)
//
#include <hip/hip_runtime.h>
#include <hip/hip_bf16.h>
#include <math.h>

typedef int   i32x4 __attribute__((ext_vector_type(4)));
typedef unsigned int u32;

#define QBF 127.0f
#define EPSF 1e-5f
#define FF 128
#define NROWS (8 * 32768)
#define NBLK 512              /* 2 blocks/CU exactly */
#define TPB 8                 /* 64-row tiles per block */

/* LDS map (bytes) — identical to R5/R12/R13/R15/R17 */
#define W2_OFF    32768
#define WBUF_OFF  49152       /* 4 waves x 4352 (16 rows x 272B) */
#define CS_OFF    66560       /* 4 x 128 f32 colsum */
#define LDS_TOTAL 68608

/* wbuf is PER-WAVE PRIVATE: the in-order LDS pipe gives same-wave
   write->read ordering; only a compiler code-motion fence is needed. */
#define WB() __builtin_amdgcn_wave_barrier()

static __device__ __forceinline__ float bcast_lane(float v, int lane) {
    return __builtin_bit_cast(float, __builtin_amdgcn_readlane(__builtin_bit_cast(int, v), lane));
}
static __device__ __forceinline__ u32 packi8(float a, float b, float c, float d, float s) {
    int i0 = (int)rintf(a * s), i1 = (int)rintf(b * s);
    int i2 = (int)rintf(c * s), i3 = (int)rintf(d * s);
    return (u32)(i0 & 0xFF) | ((u32)(i1 & 0xFF) << 8) |
           ((u32)(i2 & 0xFF) << 16) | ((u32)i3 << 24);
}

// ---------- kernel 1: weight absmean (f64, redundant per block) + quantize ----
__global__ void wquant_kernel(const float* __restrict__ W1,
                              const float* __restrict__ W2,
                              char* __restrict__ wq) {
    __shared__ double red[256];
    __shared__ float scales[2];
    const int t = threadIdx.x;

    double s = 0.0;
    #pragma unroll
    for (int i = 0; i < 32; ++i) {
        float4 v = *(const float4*)(W1 + (i * 256 + t) * 4);
        s += (double)fabsf(v.x) + (double)fabsf(v.y)
           + (double)fabsf(v.z) + (double)fabsf(v.w);
    }
    red[t] = s; __syncthreads();
    for (int o = 128; o > 0; o >>= 1) { if (t < o) red[t] += red[t + o]; __syncthreads(); }
    if (t == 0) scales[0] = 1.0f / fmaxf((float)(red[0] * (1.0 / 32768.0)), EPSF);
    __syncthreads();
    s = 0.0;
    #pragma unroll
    for (int i = 0; i < 16; ++i) {
        float4 v = *(const float4*)(W2 + (i * 256 + t) * 4);
        s += (double)fabsf(v.x) + (double)fabsf(v.y)
           + (double)fabsf(v.z) + (double)fabsf(v.w);
    }
    red[t] = s; __syncthreads();
    for (int o = 128; o > 0; o >>= 1) { if (t < o) red[t] += red[t + o]; __syncthreads(); }
    if (t == 0) scales[1] = 1.0f / fmaxf((float)(red[0] * (1.0 / 16384.0)), EPSF);
    __syncthreads();
    const float ws1 = scales[0], ws2 = scales[1];

    int g = blockIdx.x * 256 + t;                // 3072 threads
    const float* src; float wsx; char* dst;
    if (g < 2048) {
        int gi = g >> 6, l = g & 63;
        int ct = gi >> 2, kb = gi & 3;
        src = W1 + (ct * 16 + (l & 15)) * 256 + kb * 64 + (l >> 4) * 16;
        wsx = ws1;
        dst = wq + gi * 1024 + l * 16;
    } else {
        int g2 = g - 2048;
        int gi = g2 >> 6, l = g2 & 63;
        int ct = gi >> 1, kb = gi & 1;
        src = W2 + (ct * 16 + (l & 15)) * 128 + kb * 64 + (l >> 4) * 16;
        wsx = ws2;
        dst = wq + 32768 + gi * 1024 + l * 16;
    }
    u32 o[4];
    #pragma unroll
    for (int q = 0; q < 4; ++q) {
        float4 v = *(const float4*)(src + q * 4);
        float q0 = fminf(fmaxf(rintf(v.x * wsx), -1.f), 1.f);
        float q1 = fminf(fmaxf(rintf(v.y * wsx), -1.f), 1.f);
        float q2 = fminf(fmaxf(rintf(v.z * wsx), -1.f), 1.f);
        float q3 = fminf(fmaxf(rintf(v.w * wsx), -1.f), 1.f);
        o[q] = packi8(q0, q1, q2, q3, 1.0f);
    }
    *(uint4*)dst = make_uint4(o[0], o[1], o[2], o[3]);
    if (blockIdx.x == 0 && t < 2)
        ((float*)(wq + 49152))[t] = (t == 0) ? ws1 : ws2;
}

// ---------- kernel 2: fused main pass (R17 body + depth-2 register dbuf) ----
// Tile loop unrolled in pairs with statically-named buffers xrA/xrB (rule:
// runtime-indexed reg arrays spill to scratch). Each tile issues the ENTIRE
// next tile's 16 loads at its top into the other buffer -> issue-to-consume
// lead = full tile period (was ~half), ~2x outstanding bytes per wave.
#define TILE_BODY(TT, XCUR, XNXT)                                              \
{                                                                              \
    const int R0c = blockIdx.x * 512 + (TT) * 64 + w * 16;                     \
    /* ---- prefetch ENTIRE next tile into the other buffer ---- */            \
    if ((TT) + 1 < TPB) {                                                      \
        int R0n = R0c + 64;                                                    \
        _Pragma("unroll")                                                      \
        for (int r = 0; r < 16; ++r)                                           \
            XNXT[r] = *(const float4*)(srcp + (size_t)(R0n + r) * FF + lc * 4);\
    }                                                                          \
    /* ---- row absmax via LDS transpose ---- */                               \
    _Pragma("unroll")                                                          \
    for (int r = 0; r < 16; ++r) {                                             \
        float4 v = XCUR[r];                                                    \
        float m = fmaxf(fmaxf(fabsf(v.x), fabsf(v.y)),                         \
                        fmaxf(fabsf(v.z), fabsf(v.w)));                        \
        *(float*)(wbuf + r * 272 + l * 4) = m;                                 \
    }                                                                          \
    WB();                                                                      \
    float mm;                                                                  \
    {                                                                          \
        const char* p = wbuf + lr * 272 + lg * 64;                             \
        float4 a = *(const float4*)(p);                                        \
        float4 b = *(const float4*)(p + 16);                                   \
        float4 c = *(const float4*)(p + 32);                                   \
        float4 d = *(const float4*)(p + 48);                                   \
        float m0 = fmaxf(fmaxf(a.x, a.y), fmaxf(a.z, a.w));                    \
        float m1 = fmaxf(fmaxf(b.x, b.y), fmaxf(b.z, b.w));                    \
        float m2 = fmaxf(fmaxf(c.x, c.y), fmaxf(c.z, c.w));                    \
        float m3 = fmaxf(fmaxf(d.x, d.y), fmaxf(d.z, d.w));                    \
        mm = fmaxf(fmaxf(m0, m1), fmaxf(m2, m3));                              \
    }                                                                          \
    mm = fmaxf(mm, __shfl_xor(mm, 16, 64));                                    \
    mm = fmaxf(mm, __shfl_xor(mm, 32, 64));                                    \
    const float sA = QBF / fmaxf(mm, EPSF);                                    \
    const float rinv1 = 1.0f / (sA * ws1);                                     \
    WB();                                                                      \
    _Pragma("unroll")                                                          \
    for (int r = 0; r < 16; ++r) {                                             \
        float s_r = bcast_lane(sA, r);                                         \
        float4 v = XCUR[r];                                                    \
        *(u32*)(wbuf + r * 272 + l * 4) = packi8(v.x, v.y, v.z, v.w, s_r);     \
    }                                                                          \
    WB();                                                                      \
    /* ---- layer 1: i8 MFMA, K=256, W1 from LDS ---- */                       \
    i32x4 acc1[8] = {};                                                        \
    _Pragma("unroll")                                                          \
    for (int kb = 0; kb < 4; ++kb) {                                           \
        i32x4 xb = *(const i32x4*)(wbuf + lr * 272 + kb * 64 + lg * 16);       \
        _Pragma("unroll")                                                      \
        for (int ct = 0; ct < 8; ++ct) {                                       \
            i32x4 wa = *(const i32x4*)(smem + (ct * 4 + kb) * 1024 + l * 16);  \
            acc1[ct] = __builtin_amdgcn_mfma_i32_16x16x64_i8(wa, xb, acc1[ct], 0, 0, 0); \
        }                                                                      \
    }                                                                          \
    /* ---- epilogue 1 ---- */                                                 \
    float h[8][4];                                                             \
    float hmax = 0.f;                                                          \
    _Pragma("unroll")                                                          \
    for (int ct = 0; ct < 8; ++ct) {                                           \
        float4 b4 = *(const float4*)(bias1 + ct * 16 + lg * 4);                \
        h[ct][0] = fmaxf((float)acc1[ct][0] * rinv1 + b4.x, 0.f);              \
        h[ct][1] = fmaxf((float)acc1[ct][1] * rinv1 + b4.y, 0.f);              \
        h[ct][2] = fmaxf((float)acc1[ct][2] * rinv1 + b4.z, 0.f);              \
        h[ct][3] = fmaxf((float)acc1[ct][3] * rinv1 + b4.w, 0.f);              \
        hmax = fmaxf(hmax, fmaxf(fmaxf(h[ct][0], h[ct][1]),                    \
                                 fmaxf(h[ct][2], h[ct][3])));                  \
    }                                                                          \
    hmax = fmaxf(hmax, __shfl_xor(hmax, 16, 64));                              \
    hmax = fmaxf(hmax, __shfl_xor(hmax, 32, 64));                              \
    const float s2 = QBF / fmaxf(hmax, EPSF);                                  \
    const float rinv2 = 1.0f / (s2 * ws2);                                     \
    WB();                                                                      \
    _Pragma("unroll")                                                          \
    for (int ct = 0; ct < 8; ++ct)                                             \
        *(u32*)(wbuf + lr * 272 + ct * 16 + lg * 4) =                          \
            packi8(h[ct][0], h[ct][1], h[ct][2], h[ct][3], s2);                \
    /* ---- EARLY coalesced prior loads ---- */                                \
    float4 pvr[8];                                                             \
    _Pragma("unroll")                                                          \
    for (int p = 0; p < 2; ++p) {                                              \
        _Pragma("unroll")                                                      \
        for (int i = 0; i < 4; ++i) {                                          \
            int rloc = 4 * i + (l >> 4);                                       \
            pvr[p * 4 + i] = *(const float4*)(prior +                          \
                (size_t)(R0c + rloc) * FF + p * 64 + (l & 15) * 4);            \
        }                                                                      \
    }                                                                          \
    WB();                                                                      \
    /* ---- layer 2: i8 MFMA, K=128, W2 from LDS ---- */                       \
    i32x4 acc2[8] = {};                                                        \
    _Pragma("unroll")                                                          \
    for (int kb = 0; kb < 2; ++kb) {                                           \
        i32x4 hb = *(const i32x4*)(wbuf + lr * 272 + kb * 64 + lg * 16);       \
        _Pragma("unroll")                                                      \
        for (int ct = 0; ct < 8; ++ct) {                                       \
            i32x4 wa = *(const i32x4*)(smem + W2_OFF + (ct * 2 + kb) * 1024 + l * 16); \
            acc2[ct] = __builtin_amdgcn_mfma_i32_16x16x64_i8(wa, hb, acc2[ct], 0, 0, 0); \
        }                                                                      \
    }                                                                          \
    /* ---- epilogue 2 ---- */                                                 \
    _Pragma("unroll")                                                          \
    for (int p = 0; p < 2; ++p) {                                              \
        WB();                                                                  \
        _Pragma("unroll")                                                      \
        for (int c = 0; c < 4; ++c) {                                          \
            const int ct = 4 * p + c;                                          \
            float4 b4 = *(const float4*)(bias2 + ct * 16 + lg * 4);            \
            float4 lik;                                                        \
            float y0 = (float)acc2[ct][0] * rinv2 + b4.x;                      \
            float y1 = (float)acc2[ct][1] * rinv2 + b4.y;                      \
            float y2 = (float)acc2[ct][2] * rinv2 + b4.z;                      \
            float y3 = (float)acc2[ct][3] * rinv2 + b4.w;                      \
            lik.x = __builtin_amdgcn_rcpf(1.0f + __expf(-y0));                 \
            lik.y = __builtin_amdgcn_rcpf(1.0f + __expf(-y1));                 \
            lik.z = __builtin_amdgcn_rcpf(1.0f + __expf(-y2));                 \
            lik.w = __builtin_amdgcn_rcpf(1.0f + __expf(-y3));                 \
            *(float4*)(wbuf + lr * 272 + c * 64 + lg * 16) = lik;              \
        }                                                                      \
        WB();                                                                  \
        _Pragma("unroll")                                                      \
        for (int i = 0; i < 4; ++i) {                                          \
            int rloc = 4 * i + (l >> 4);                                       \
            float4 lk = *(const float4*)(wbuf + rloc * 272 + (l & 15) * 16);   \
            float4 pv = pvr[p * 4 + i];                                        \
            float4 un;                                                         \
            un.x = pv.x * lk.x; un.y = pv.y * lk.y;                            \
            un.z = pv.z * lk.z; un.w = pv.w * lk.w;                            \
            *(float4*)(out + (size_t)(R0c + rloc) * FF + p * 64 + (l & 15) * 4) = un; \
            cs[p].x += un.x; cs[p].y += un.y;                                  \
            cs[p].z += un.z; cs[p].w += un.w;                                  \
        }                                                                      \
    }                                                                          \
    WB();                                                                      \
}

__global__ __launch_bounds__(256, 2) void fused_kernel(
    const float* __restrict__ evid, const float* __restrict__ prior,
    const float* __restrict__ bias1, const float* __restrict__ bias2,
    const char* __restrict__ wq, float* __restrict__ out,
    float* __restrict__ partials)
{
    __shared__ __align__(16) char smem[LDS_TOTAL];
    const int tid = threadIdx.x;
    const int w = tid >> 6, l = tid & 63;
    const int lr = l & 15, lg = l >> 4;
    const int lc = l & 31, half = l >> 5;
    char* wbuf = smem + WBUF_OFF + w * 4352;
    float* colsum = (float*)(smem + CS_OFF);
    const float ws1 = ((const float*)(wq + 49152))[0];
    const float ws2 = ((const float*)(wq + 49152))[1];

    // stage 48KB of i8 weights (linear copy, granule layout preserved)
    {
        const uint4* g = (const uint4*)wq;
        #pragma unroll
        for (int i = 0; i < 12; ++i) {
            uint4 v = g[i * 256 + tid];
            *(uint4*)(smem + (size_t)(i * 256 + tid) * 16) = v;
        }
    }
    const float* srcp = half ? evid : prior;
    // tile-0 loads into buffer A (overlap staging latency)
    float4 xrA[16], xrB[16];
    {
        int R0 = blockIdx.x * 512 + w * 16;
        #pragma unroll
        for (int r = 0; r < 16; ++r)
            xrA[r] = *(const float4*)(srcp + (size_t)(R0 + r) * FF + lc * 4);
    }
    __syncthreads();   // cross-wave: weights staged

    float4 cs[2];
    cs[0] = make_float4(0.f, 0.f, 0.f, 0.f);
    cs[1] = make_float4(0.f, 0.f, 0.f, 0.f);

    #pragma unroll
    for (int tp = 0; tp < TPB; tp += 2) {
        TILE_BODY(tp,     xrA, xrB);
        TILE_BODY(tp + 1, xrB, xrA);
    }

    // ---- column sums: cs lanes share cols across row-groups (xor 16,32) ----
    #pragma unroll
    for (int p = 0; p < 2; ++p) {
        cs[p].x += __shfl_xor(cs[p].x, 16, 64);
        cs[p].y += __shfl_xor(cs[p].y, 16, 64);
        cs[p].z += __shfl_xor(cs[p].z, 16, 64);
        cs[p].w += __shfl_xor(cs[p].w, 16, 64);
        cs[p].x += __shfl_xor(cs[p].x, 32, 64);
        cs[p].y += __shfl_xor(cs[p].y, 32, 64);
        cs[p].z += __shfl_xor(cs[p].z, 32, 64);
        cs[p].w += __shfl_xor(cs[p].w, 32, 64);
    }
    if (l < 16) {
        *(float4*)(colsum + w * 128 + l * 4) = cs[0];
        *(float4*)(colsum + w * 128 + 64 + l * 4) = cs[1];
    }
    __syncthreads();   // cross-wave: colsum combine
    if (tid < FF) {
        float p = colsum[tid] + colsum[128 + tid]
                + colsum[256 + tid] + colsum[384 + tid];
        partials[(size_t)blockIdx.x * FF + tid] = p;
    }
}

// ---------- kernel 3: deterministic normalizer (batch b <- 64 block partials) ----
__global__ void norm_kernel(const float* __restrict__ partials, float* __restrict__ norm) {
    __shared__ float red[2][128];
    int b = blockIdx.x;                                // 8 blocks x 256 thr
    int f = threadIdx.x & 127, tg = threadIdx.x >> 7;
    float s = 0.f;
    for (int t = tg * 32; t < tg * 32 + 32; ++t)
        s += partials[((size_t)b * 64 + t) * FF + f];
    red[tg][f] = s; __syncthreads();
    if (tg == 0)
        norm[b * FF + f] = fmaxf(red[0][f] + red[1][f], 1e-10f);
}

// ---------- kernel 4: out /= norm ----------
__global__ void div_kernel(float* __restrict__ out, const float* __restrict__ norm) {
    size_t i4 = (size_t)blockIdx.x * blockDim.x + threadIdx.x;
    const size_t total4 = (size_t)NROWS * FF / 4;
    for (; i4 < total4; i4 += (size_t)gridDim.x * blockDim.x) {
        size_t i = i4 * 4;
        float4 v = *(float4*)(out + i);
        int b = (int)(i >> 22);                  // S*F = 2^22
        int f = (int)(i & 127);
        float4 nv = *(const float4*)(norm + b * FF + f);
        v.x /= nv.x; v.y /= nv.y; v.z /= nv.z; v.w /= nv.w;
        *(float4*)(out + i) = v;
    }
}

extern "C" void kernel_launch(void* const* d_in, const int* in_sizes, int n_in,
                              void* d_out, int out_size, void* d_ws, size_t ws_size,
                              hipStream_t stream) {
    const float* evid  = (const float*)d_in[0];
    const float* prior = (const float*)d_in[1];
    const float* W1    = (const float*)d_in[2];
    const float* b1    = (const float*)d_in[3];
    const float* W2    = (const float*)d_in[4];
    const float* b2    = (const float*)d_in[5];
    float* out = (float*)d_out;

    char* ws = (char*)d_ws;
    char*   wq       = ws;                               // 48 KB granules + 8B scales @49152
    float*  partials = (float*)(ws + 65536);             // 512*128*4 = 256 KB
    float*  norm     = (float*)(ws + 65536 + 262144);    // 4 KB

    wquant_kernel<<<12, 256, 0, stream>>>(W1, W2, wq);
    fused_kernel<<<NBLK, 256, 0, stream>>>(evid, prior, b1, b2, wq, out, partials);
    norm_kernel<<<8, 256, 0, stream>>>(partials, norm);
    div_kernel<<<2048, 256, 0, stream>>>(out, norm);
}

// Round 19
// 146.244 us; speedup vs baseline: 1.2516x; 1.2516x over previous
//
#include <hip/hip_runtime.h>
#include <hip/hip_bf16.h>
#include <math.h>

typedef int   i32x4 __attribute__((ext_vector_type(4)));
typedef unsigned int u32;

#define QBF 127.0f
#define EPSF 1e-5f
#define FF 128
#define NROWS (8 * 32768)
#define NBLK 512              /* 2 blocks/CU exactly */
#define TPB 8                 /* 64-row tiles per block */

/* LDS map (bytes) — identical to R5/R12/R13/R15 */
#define W2_OFF    32768
#define WBUF_OFF  49152       /* 4 waves x 4352 (16 rows x 272B) */
#define CS_OFF    66560       /* 4 x 128 f32 colsum */
#define LDS_TOTAL 68608

/* wbuf is PER-WAVE PRIVATE: the in-order LDS pipe gives same-wave
   write->read ordering; only a compiler code-motion fence is needed. */
#define WB() __builtin_amdgcn_wave_barrier()

static __device__ __forceinline__ float bcast_lane(float v, int lane) {
    return __builtin_bit_cast(float, __builtin_amdgcn_readlane(__builtin_bit_cast(int, v), lane));
}
static __device__ __forceinline__ u32 packi8(float a, float b, float c, float d, float s) {
    int i0 = (int)rintf(a * s), i1 = (int)rintf(b * s);
    int i2 = (int)rintf(c * s), i3 = (int)rintf(d * s);
    return (u32)(i0 & 0xFF) | ((u32)(i1 & 0xFF) << 8) |
           ((u32)(i2 & 0xFF) << 16) | ((u32)i3 << 24);
}

// ---------- kernel 1: weight absmean (f64, redundant per block) + quantize ----
// Each of the 12 blocks recomputes both absmeans itself (48K f32, L3-hot
// after the first block) -- removes the separate wstats launch. f64 tree
// order perturbation ~1e-13 relative; cannot flip rintf ties (verified
// across three summation orders in R1/R2/R5, identical absmax).
__global__ void wquant_kernel(const float* __restrict__ W1,
                              const float* __restrict__ W2,
                              char* __restrict__ wq) {
    __shared__ double red[256];
    __shared__ float scales[2];
    const int t = threadIdx.x;

    // absmean W1: 32768 elems = 8192 float4, 32 per thread
    double s = 0.0;
    #pragma unroll
    for (int i = 0; i < 32; ++i) {
        float4 v = *(const float4*)(W1 + (i * 256 + t) * 4);
        s += (double)fabsf(v.x) + (double)fabsf(v.y)
           + (double)fabsf(v.z) + (double)fabsf(v.w);
    }
    red[t] = s; __syncthreads();
    for (int o = 128; o > 0; o >>= 1) { if (t < o) red[t] += red[t + o]; __syncthreads(); }
    if (t == 0) scales[0] = 1.0f / fmaxf((float)(red[0] * (1.0 / 32768.0)), EPSF);
    __syncthreads();
    // absmean W2: 16384 elems = 4096 float4, 16 per thread
    s = 0.0;
    #pragma unroll
    for (int i = 0; i < 16; ++i) {
        float4 v = *(const float4*)(W2 + (i * 256 + t) * 4);
        s += (double)fabsf(v.x) + (double)fabsf(v.y)
           + (double)fabsf(v.z) + (double)fabsf(v.w);
    }
    red[t] = s; __syncthreads();
    for (int o = 128; o > 0; o >>= 1) { if (t < o) red[t] += red[t + o]; __syncthreads(); }
    if (t == 0) scales[1] = 1.0f / fmaxf((float)(red[0] * (1.0 / 16384.0)), EPSF);
    __syncthreads();
    const float ws1 = scales[0], ws2 = scales[1];

    // quantize this block's granule share (layout identical to R15)
    int g = blockIdx.x * 256 + t;                // 3072 threads
    const float* src; float wsx; char* dst;
    if (g < 2048) {
        int gi = g >> 6, l = g & 63;
        int ct = gi >> 2, kb = gi & 3;
        src = W1 + (ct * 16 + (l & 15)) * 256 + kb * 64 + (l >> 4) * 16;
        wsx = ws1;
        dst = wq + gi * 1024 + l * 16;
    } else {
        int g2 = g - 2048;
        int gi = g2 >> 6, l = g2 & 63;
        int ct = gi >> 1, kb = gi & 1;
        src = W2 + (ct * 16 + (l & 15)) * 128 + kb * 64 + (l >> 4) * 16;
        wsx = ws2;
        dst = wq + 32768 + gi * 1024 + l * 16;
    }
    u32 o[4];
    #pragma unroll
    for (int q = 0; q < 4; ++q) {
        float4 v = *(const float4*)(src + q * 4);
        float q0 = fminf(fmaxf(rintf(v.x * wsx), -1.f), 1.f);
        float q1 = fminf(fmaxf(rintf(v.y * wsx), -1.f), 1.f);
        float q2 = fminf(fmaxf(rintf(v.z * wsx), -1.f), 1.f);
        float q3 = fminf(fmaxf(rintf(v.w * wsx), -1.f), 1.f);
        o[q] = packi8(q0, q1, q2, q3, 1.0f);
    }
    *(uint4*)dst = make_uint4(o[0], o[1], o[2], o[3]);
    // publish scales once (block 0) for the fused kernel's epilogue math
    if (blockIdx.x == 0 && t < 2)
        ((float*)(wq + 49152))[t] = (t == 0) ? ws1 : ws2;
}

// ---------- kernel 2: fused main pass (R15 body, byte-identical) ----------
__global__ __launch_bounds__(256, 2) void fused_kernel(
    const float* __restrict__ evid, const float* __restrict__ prior,
    const float* __restrict__ bias1, const float* __restrict__ bias2,
    const char* __restrict__ wq, float* __restrict__ out,
    float* __restrict__ partials)
{
    __shared__ __align__(16) char smem[LDS_TOTAL];
    const int tid = threadIdx.x;
    const int w = tid >> 6, l = tid & 63;
    const int lr = l & 15, lg = l >> 4;
    const int lc = l & 31, half = l >> 5;
    char* wbuf = smem + WBUF_OFF + w * 4352;
    float* colsum = (float*)(smem + CS_OFF);
    const float ws1 = ((const float*)(wq + 49152))[0];
    const float ws2 = ((const float*)(wq + 49152))[1];

    // stage 48KB of i8 weights (linear copy, granule layout preserved)
    {
        const uint4* g = (const uint4*)wq;
        #pragma unroll
        for (int i = 0; i < 12; ++i) {
            uint4 v = g[i * 256 + tid];
            *(uint4*)(smem + (size_t)(i * 256 + tid) * 16) = v;
        }
    }
    // first tile x loads (overlap staging latency)
    float4 xr[16];
    {
        const float* srcp = half ? evid : prior;
        int R0 = blockIdx.x * 512 + w * 16;
        #pragma unroll
        for (int r = 0; r < 16; ++r)
            xr[r] = *(const float4*)(srcp + (size_t)(R0 + r) * FF + lc * 4);
    }
    __syncthreads();   // cross-wave: weights staged

    float4 cs[2];
    cs[0] = make_float4(0.f, 0.f, 0.f, 0.f);
    cs[1] = make_float4(0.f, 0.f, 0.f, 0.f);

    for (int t = 0; t < TPB; ++t) {
        const int R0c = blockIdx.x * 512 + t * 64 + w * 16;

        // ---- row absmax via LDS transpose (per-wave private buffer) ----
        #pragma unroll
        for (int r = 0; r < 16; ++r) {
            float4 v = xr[r];
            float m = fmaxf(fmaxf(fabsf(v.x), fabsf(v.y)),
                            fmaxf(fabsf(v.z), fabsf(v.w)));
            *(float*)(wbuf + r * 272 + l * 4) = m;
        }
        WB();
        float mm;
        {
            const char* p = wbuf + lr * 272 + lg * 64;
            float4 a = *(const float4*)(p);
            float4 b = *(const float4*)(p + 16);
            float4 c = *(const float4*)(p + 32);
            float4 d = *(const float4*)(p + 48);
            float m0 = fmaxf(fmaxf(a.x, a.y), fmaxf(a.z, a.w));
            float m1 = fmaxf(fmaxf(b.x, b.y), fmaxf(b.z, b.w));
            float m2 = fmaxf(fmaxf(c.x, c.y), fmaxf(c.z, c.w));
            float m3 = fmaxf(fmaxf(d.x, d.y), fmaxf(d.z, d.w));
            mm = fmaxf(fmaxf(m0, m1), fmaxf(m2, m3));
        }
        mm = fmaxf(mm, __shfl_xor(mm, 16, 64));
        mm = fmaxf(mm, __shfl_xor(mm, 32, 64));     // lanes of row lr agree
        const float sA = QBF / fmaxf(mm, EPSF);
        const float rinv1 = 1.0f / (sA * ws1);

        // ---- quantize x -> i8 rows [16][256B @272 stride] ----
        WB();
        #pragma unroll
        for (int r = 0; r < 16; ++r) {
            float s_r = bcast_lane(sA, r);
            float4 v = xr[r];
            *(u32*)(wbuf + r * 272 + l * 4) = packi8(v.x, v.y, v.z, v.w, s_r);
        }

        // ---- prefetch half 1 (rows 0-7 of next tile) ----
        if (t + 1 < TPB) {
            const float* srcp = half ? evid : prior;
            int R0n = blockIdx.x * 512 + (t + 1) * 64 + w * 16;
            #pragma unroll
            for (int r = 0; r < 8; ++r)
                xr[r] = *(const float4*)(srcp + (size_t)(R0n + r) * FF + lc * 4);
        }
        WB();   // xq writes ordered before layer-1 ds_reads

        // ---- layer 1: i8 MFMA, K=256 (4 x 64), W1 from LDS ----
        i32x4 acc1[8] = {};
        #pragma unroll
        for (int kb = 0; kb < 4; ++kb) {
            i32x4 xb = *(const i32x4*)(wbuf + lr * 272 + kb * 64 + lg * 16);
            #pragma unroll
            for (int ct = 0; ct < 8; ++ct) {
                i32x4 wa = *(const i32x4*)(smem + (ct * 4 + kb) * 1024 + l * 16);
                acc1[ct] = __builtin_amdgcn_mfma_i32_16x16x64_i8(wa, xb, acc1[ct], 0, 0, 0);
            }
        }

        // ---- epilogue 1: exact scale + bias + relu, lane-local requant ----
        float h[8][4];
        float hmax = 0.f;
        #pragma unroll
        for (int ct = 0; ct < 8; ++ct) {
            float4 b4 = *(const float4*)(bias1 + ct * 16 + lg * 4);
            h[ct][0] = fmaxf((float)acc1[ct][0] * rinv1 + b4.x, 0.f);
            h[ct][1] = fmaxf((float)acc1[ct][1] * rinv1 + b4.y, 0.f);
            h[ct][2] = fmaxf((float)acc1[ct][2] * rinv1 + b4.z, 0.f);
            h[ct][3] = fmaxf((float)acc1[ct][3] * rinv1 + b4.w, 0.f);
            hmax = fmaxf(hmax, fmaxf(fmaxf(h[ct][0], h[ct][1]),
                                     fmaxf(h[ct][2], h[ct][3])));
        }
        hmax = fmaxf(hmax, __shfl_xor(hmax, 16, 64));
        hmax = fmaxf(hmax, __shfl_xor(hmax, 32, 64));
        const float s2 = QBF / fmaxf(hmax, EPSF);
        const float rinv2 = 1.0f / (s2 * ws2);

        // ---- hq -> LDS rows (same-wave in-order = WAR-safe) ----
        WB();
        #pragma unroll
        for (int ct = 0; ct < 8; ++ct)
            *(u32*)(wbuf + lr * 272 + ct * 16 + lg * 4) =
                packi8(h[ct][0], h[ct][1], h[ct][2], h[ct][3], s2);

        // ---- prefetch half 2 (rows 8-15) + EARLY coalesced prior loads ----
        if (t + 1 < TPB) {
            const float* srcp = half ? evid : prior;
            int R0n = blockIdx.x * 512 + (t + 1) * 64 + w * 16;
            #pragma unroll
            for (int r = 8; r < 16; ++r)
                xr[r] = *(const float4*)(srcp + (size_t)(R0n + r) * FF + lc * 4);
        }
        float4 pvr[8];
        #pragma unroll
        for (int p = 0; p < 2; ++p) {
            #pragma unroll
            for (int i = 0; i < 4; ++i) {
                int rloc = 4 * i + (l >> 4);
                pvr[p * 4 + i] = *(const float4*)(prior +
                    (size_t)(R0c + rloc) * FF + p * 64 + (l & 15) * 4);
            }
        }
        WB();   // hq writes ordered before layer-2 ds_reads

        // ---- layer 2: i8 MFMA, K=128 (2 x 64), W2 from LDS ----
        i32x4 acc2[8] = {};
        #pragma unroll
        for (int kb = 0; kb < 2; ++kb) {
            i32x4 hb = *(const i32x4*)(wbuf + lr * 272 + kb * 64 + lg * 16);
            #pragma unroll
            for (int ct = 0; ct < 8; ++ct) {
                i32x4 wa = *(const i32x4*)(smem + W2_OFF + (ct * 2 + kb) * 1024 + l * 16);
                acc2[ct] = __builtin_amdgcn_mfma_i32_16x16x64_i8(wa, hb, acc2[ct], 0, 0, 0);
            }
        }

        // ---- epilogue 2: lik -> wbuf transpose -> *prior -> coalesced store ----
        #pragma unroll
        for (int p = 0; p < 2; ++p) {
            WB();   // previous-pass reads ordered before lik overwrite (WAR)
            #pragma unroll
            for (int c = 0; c < 4; ++c) {
                const int ct = 4 * p + c;
                float4 b4 = *(const float4*)(bias2 + ct * 16 + lg * 4);
                float4 lik;
                float y0 = (float)acc2[ct][0] * rinv2 + b4.x;
                float y1 = (float)acc2[ct][1] * rinv2 + b4.y;
                float y2 = (float)acc2[ct][2] * rinv2 + b4.z;
                float y3 = (float)acc2[ct][3] * rinv2 + b4.w;
                lik.x = __builtin_amdgcn_rcpf(1.0f + __expf(-y0));
                lik.y = __builtin_amdgcn_rcpf(1.0f + __expf(-y1));
                lik.z = __builtin_amdgcn_rcpf(1.0f + __expf(-y2));
                lik.w = __builtin_amdgcn_rcpf(1.0f + __expf(-y3));
                *(float4*)(wbuf + lr * 272 + c * 64 + lg * 16) = lik;
            }
            WB();   // lik writes ordered before transposed reads
            #pragma unroll
            for (int i = 0; i < 4; ++i) {
                int rloc = 4 * i + (l >> 4);
                float4 lk = *(const float4*)(wbuf + rloc * 272 + (l & 15) * 16);
                float4 pv = pvr[p * 4 + i];
                float4 un;
                un.x = pv.x * lk.x; un.y = pv.y * lk.y;
                un.z = pv.z * lk.z; un.w = pv.w * lk.w;
                *(float4*)(out + (size_t)(R0c + rloc) * FF + p * 64 + (l & 15) * 4) = un;
                cs[p].x += un.x; cs[p].y += un.y;
                cs[p].z += un.z; cs[p].w += un.w;
            }
        }
        WB();   // epilogue reads ordered before next tile's max writes (WAR)
    }

    // ---- column sums: cs lanes share cols across row-groups (xor 16,32) ----
    #pragma unroll
    for (int p = 0; p < 2; ++p) {
        cs[p].x += __shfl_xor(cs[p].x, 16, 64);
        cs[p].y += __shfl_xor(cs[p].y, 16, 64);
        cs[p].z += __shfl_xor(cs[p].z, 16, 64);
        cs[p].w += __shfl_xor(cs[p].w, 16, 64);
        cs[p].x += __shfl_xor(cs[p].x, 32, 64);
        cs[p].y += __shfl_xor(cs[p].y, 32, 64);
        cs[p].z += __shfl_xor(cs[p].z, 32, 64);
        cs[p].w += __shfl_xor(cs[p].w, 32, 64);
    }
    if (l < 16) {
        *(float4*)(colsum + w * 128 + l * 4) = cs[0];
        *(float4*)(colsum + w * 128 + 64 + l * 4) = cs[1];
    }
    __syncthreads();   // cross-wave: colsum combine
    if (tid < FF) {
        float p = colsum[tid] + colsum[128 + tid]
                + colsum[256 + tid] + colsum[384 + tid];
        partials[(size_t)blockIdx.x * FF + tid] = p;
    }
}

// ---------- kernel 3: deterministic normalizer (batch b <- 64 block partials) ----
__global__ void norm_kernel(const float* __restrict__ partials, float* __restrict__ norm) {
    __shared__ float red[2][128];
    int b = blockIdx.x;                                // 8 blocks x 256 thr
    int f = threadIdx.x & 127, tg = threadIdx.x >> 7;
    float s = 0.f;
    for (int t = tg * 32; t < tg * 32 + 32; ++t)
        s += partials[((size_t)b * 64 + t) * FF + f];
    red[tg][f] = s; __syncthreads();
    if (tg == 0)
        norm[b * FF + f] = fmaxf(red[0][f] + red[1][f], 1e-10f);
}

// ---------- kernel 4: out /= norm ----------
__global__ void div_kernel(float* __restrict__ out, const float* __restrict__ norm) {
    size_t i4 = (size_t)blockIdx.x * blockDim.x + threadIdx.x;
    const size_t total4 = (size_t)NROWS * FF / 4;
    for (; i4 < total4; i4 += (size_t)gridDim.x * blockDim.x) {
        size_t i = i4 * 4;
        float4 v = *(float4*)(out + i);
        int b = (int)(i >> 22);                  // S*F = 2^22
        int f = (int)(i & 127);
        float4 nv = *(const float4*)(norm + b * FF + f);
        v.x /= nv.x; v.y /= nv.y; v.z /= nv.z; v.w /= nv.w;
        *(float4*)(out + i) = v;
    }
}

extern "C" void kernel_launch(void* const* d_in, const int* in_sizes, int n_in,
                              void* d_out, int out_size, void* d_ws, size_t ws_size,
                              hipStream_t stream) {
    const float* evid  = (const float*)d_in[0];
    const float* prior = (const float*)d_in[1];
    const float* W1    = (const float*)d_in[2];
    const float* b1    = (const float*)d_in[3];
    const float* W2    = (const float*)d_in[4];
    const float* b2    = (const float*)d_in[5];
    float* out = (float*)d_out;

    char* ws = (char*)d_ws;
    char*   wq       = ws;                               // 48 KB granules + 8B scales @49152
    float*  partials = (float*)(ws + 65536);             // 512*128*4 = 256 KB
    float*  norm     = (float*)(ws + 65536 + 262144);    // 4 KB

    wquant_kernel<<<12, 256, 0, stream>>>(W1, W2, wq);
    fused_kernel<<<NBLK, 256, 0, stream>>>(evid, prior, b1, b2, wq, out, partials);
    norm_kernel<<<8, 256, 0, stream>>>(partials, norm);
    div_kernel<<<2048, 256, 0, stream>>>(out, norm);
}